// Round 1
// baseline (922.783 us; speedup 1.0000x reference)
//
#include <hip/hip_runtime.h>

#define BB 8
#define NN 4096
#define DD 256
#define HH 4
#define DHH 64
#define KPP 256
#define KNN 128

typedef float f32x4 __attribute__((ext_vector_type(4)));
typedef short bf16x8 __attribute__((ext_vector_type(8)));

#define FLAG_TRANSB 1
#define FLAG_RELU   2

__device__ __forceinline__ float bf2f(unsigned short u){
  union { unsigned int i; float f; } v; v.i = ((unsigned int)u) << 16; return v.f;
}
__device__ __forceinline__ unsigned short f2bf(float f){
  union { float f; unsigned int i; } v; v.f = f;
  return (unsigned short)((v.i + 0x7FFFu + ((v.i >> 16) & 1u)) >> 16);
}

// ---------------- masked-mean stats (2-stage) ----------------
__global__ void stats_part(const float* __restrict__ x, const int* __restrict__ mask,
                           float* __restrict__ part, float* __restrict__ pcnt){
  int b = blockIdx.y, c = blockIdx.x, d = threadIdx.x;
  int n0 = c * 128;
  float sp = 0.f, sn = 0.f; int cp = 0, cn = 0;
  const float* xb = x + ((long)b*NN + n0)*DD + d;
  const int* mb = mask + (long)b*NN + n0;
  for (int r = 0; r < 128; r++){
    int mv = mb[r];
    float v = xb[(long)r*DD];
    if (mv == 1){ sp += v; cp++; }
    else if (mv == -1){ sn += v; cn++; }
  }
  part[(((long)(b*32+c)*2+0)*DD)+d] = sp;
  part[(((long)(b*32+c)*2+1)*DD)+d] = sn;
  if (d == 0){ pcnt[(b*32+c)*2+0] = (float)cp; pcnt[(b*32+c)*2+1] = (float)cn; }
}

__global__ void stats_final(const float* __restrict__ part, const float* __restrict__ pcnt,
                            float* __restrict__ posq){
  int b = blockIdx.x, d = threadIdx.x;
  float sp=0.f, sn=0.f, cp=0.f, cn=0.f;
  for (int c = 0; c < 32; c++){
    sp += part[(((long)(b*32+c)*2+0)*DD)+d];
    sn += part[(((long)(b*32+c)*2+1)*DD)+d];
    cp += pcnt[(b*32+c)*2+0];
    cn += pcnt[(b*32+c)*2+1];
  }
  posq[(long)(b*2+0)*DD + d] = sp / (cp + 1e-6f);
  posq[(long)(b*2+1)*DD + d] = sn / (cn + 1e-6f);
}

// ---------------- sim vectors: v = W @ q, c = b . q ----------------
__global__ void sim_vec(const float* __restrict__ Wp, const float* __restrict__ bp,
                        const float* __restrict__ Wn, const float* __restrict__ bn,
                        const float* __restrict__ posq, float* __restrict__ vvec,
                        float* __restrict__ cscal){
  int b = blockIdx.x, k = threadIdx.x;
  const float* qp = posq + (long)(b*2+0)*DD;
  const float* qn = posq + (long)(b*2+1)*DD;
  float vp = 0.f, vn = 0.f;
  for (int j = 0; j < DD; j++){ vp += Wp[(long)k*DD+j]*qp[j]; vn += Wn[(long)k*DD+j]*qn[j]; }
  vvec[(long)(b*2+0)*DD+k] = vp; vvec[(long)(b*2+1)*DD+k] = vn;
  __shared__ float red[256];
  red[k] = bp[k]*qp[k];
  __syncthreads();
  for (int s = 128; s > 0; s >>= 1){ if (k < s) red[k] += red[k+s]; __syncthreads(); }
  if (k == 0) cscal[b*2+0] = red[0];
  __syncthreads();
  red[k] = bn[k]*qn[k];
  __syncthreads();
  for (int s = 128; s > 0; s >>= 1){ if (k < s) red[k] += red[k+s]; __syncthreads(); }
  if (k == 0) cscal[b*2+1] = red[0];
}

// ---------------- sims: sigmoid(x . v + c) ----------------
__global__ void sim_kernel(const float* __restrict__ x, const float* __restrict__ vvec,
                           const float* __restrict__ cscal,
                           float* __restrict__ simP, float* __restrict__ simN){
  int b = blockIdx.y;
  int w = threadIdx.x >> 6, lane = threadIdx.x & 63;
  int n = blockIdx.x*4 + w;
  const float4* xr = (const float4*)(x + ((long)b*NN + n)*DD);
  const float4* vp = (const float4*)(vvec + (long)(b*2+0)*DD);
  const float4* vn = (const float4*)(vvec + (long)(b*2+1)*DD);
  float4 xv = xr[lane];
  float4 a = vp[lane], c = vn[lane];
  float sp = xv.x*a.x + xv.y*a.y + xv.z*a.z + xv.w*a.w;
  float sn = xv.x*c.x + xv.y*c.y + xv.z*c.z + xv.w*c.w;
  for (int off = 32; off; off >>= 1){ sp += __shfl_xor(sp, off); sn += __shfl_xor(sn, off); }
  if (lane == 0){
    float zp = sp + cscal[b*2+0], zn = sn + cscal[b*2+1];
    simP[(long)b*NN+n] = 1.f/(1.f+expf(-zp));
    simN[(long)b*NN+n] = 1.f/(1.f+expf(-zn));
  }
}

// ---------------- per-batch top-k via bitonic sort ----------------
__global__ __launch_bounds__(512) void topk_kernel(const float* __restrict__ simP,
                                                   const float* __restrict__ simN,
                                                   int* __restrict__ idxb, float* __restrict__ wb){
  __shared__ float v[4096];
  __shared__ int ix[4096];
  int sgn = blockIdx.x, b = blockIdx.y, t = threadIdx.x;
  const float* s = (sgn == 0 ? simP : simN) + (long)b*NN;
  for (int i = t; i < 4096; i += 512){ v[i] = s[i]; ix[i] = i; }
  __syncthreads();
  for (int k = 2; k <= 4096; k <<= 1){
    for (int j = k >> 1; j > 0; j >>= 1){
      for (int i = t; i < 4096; i += 512){
        int l = i ^ j;
        if (l > i){
          bool dir = ((i & k) == 0);   // descending region
          float va = v[i], vb = v[l]; int ia = ix[i], ib = ix[l];
          bool g = (va > vb) || (va == vb && ia < ib);
          if (g != dir){ v[i] = vb; v[l] = va; ix[i] = ib; ix[l] = ia; }
        }
      }
      __syncthreads();
    }
  }
  int K = (sgn == 0) ? KPP : KNN;
  for (int i = t; i < K; i += 512){
    idxb[(long)(b*2+sgn)*256+i] = ix[i];
    wb[(long)(b*2+sgn)*256+i] = v[i];
  }
}

// ---------------- gather masked nodes ----------------
__global__ void gather_nodes(const float* __restrict__ x, const int* __restrict__ idxb,
                             const float* __restrict__ wb,
                             float* __restrict__ node_p, float* __restrict__ node_n){
  int b = blockIdx.y, i = blockIdx.x, d = threadIdx.x;
  int sgn = (i < KPP) ? 0 : 1;
  int ii = (sgn == 0) ? i : i - KPP;
  int idx = idxb[(long)(b*2+sgn)*256+ii];
  float w = wb[(long)(b*2+sgn)*256+ii];
  float val = (w > 0.6f) ? x[((long)b*NN + idx)*DD + d] : 0.f;
  if (sgn == 0) node_p[((long)b*KPP+ii)*DD+d] = val;
  else          node_n[((long)b*KNN+ii)*DD+d] = val;
}

// ---------------- row softmax (batched with batch stride) ----------------
__global__ void softmax_rows(float* __restrict__ A, int L, int rpb, long bstride, int rows){
  int w = threadIdx.x >> 6, lane = threadIdx.x & 63;
  long row = (long)blockIdx.x*4 + w;
  if (row >= rows) return;
  int b = (int)(row / rpb), r = (int)(row % rpb);
  float* a = A + (long)b*bstride + (long)r*L;
  int e = L >> 6;
  float vals[4]; float mx = -1e30f;
  for (int j = 0; j < e; j++){ vals[j] = a[lane*e+j]; mx = fmaxf(mx, vals[j]); }
  for (int off = 32; off; off >>= 1) mx = fmaxf(mx, __shfl_xor(mx, off));
  float sum = 0.f;
  for (int j = 0; j < e; j++){ vals[j] = expf(vals[j]-mx); sum += vals[j]; }
  for (int off = 32; off; off >>= 1) sum += __shfl_xor(sum, off);
  float rinv = 1.f/sum;
  for (int j = 0; j < e; j++) a[lane*e+j] = vals[j]*rinv;
}

// ---------------- add gathered pos_emb to query ----------------
__global__ void add_posemb(float* __restrict__ query, const int* __restrict__ idxb,
                           const float* __restrict__ pe){
  int b = blockIdx.y, i = blockIdx.x, d = threadIdx.x;
  int sgn = (i < KPP) ? 0 : 1;
  int ii = (sgn == 0) ? i : i - KPP;
  int idx = idxb[(long)(b*2+sgn)*256+ii];
  query[((long)b*384+i)*DD + d] += pe[(long)idx*DD + d];
}

// ---------------- row LayerNorm core (no affine) f32 -> bf16 ----------------
__global__ void rownorm_kernel(const float* __restrict__ X, unsigned short* __restrict__ Y, int rows){
  int w = threadIdx.x >> 6, lane = threadIdx.x & 63;
  long row = (long)blockIdx.x*4 + w;
  if (row >= rows) return;
  const float4* xr = (const float4*)(X + row*DD);
  float4 xv = xr[lane];
  float s = xv.x+xv.y+xv.z+xv.w;
  float q = xv.x*xv.x+xv.y*xv.y+xv.z*xv.z+xv.w*xv.w;
  for (int off = 32; off; off >>= 1){ s += __shfl_xor(s, off); q += __shfl_xor(q, off); }
  float m = s*(1.f/256.f);
  float var = q*(1.f/256.f) - m*m;
  float rinv = rsqrtf(var + 1e-5f);
  ushort4 o;
  o.x = f2bf((xv.x-m)*rinv); o.y = f2bf((xv.y-m)*rinv);
  o.z = f2bf((xv.z-m)*rinv); o.w = f2bf((xv.w-m)*rinv);
  ((ushort4*)(Y + row*DD))[lane] = o;
}

// ---------------- generic bf16-MFMA GEMM ----------------
// C = R + gate .* ( relu?( alpha*(A'@B(^T)) + bias ) ), A' = A*lnG + lnB (per-k)
template<typename AT, typename OT>
__global__ __launch_bounds__(256) void gemm_kernel(
    const AT* __restrict__ A, long sAb, int lda,
    const float* __restrict__ Bm, long sBb, int ldb,
    OT* __restrict__ C, long sCb, int ldc,
    const float* __restrict__ R, long sRb, int ldr,
    const float* __restrict__ lnG, const float* __restrict__ lnBv,
    const float* __restrict__ bias, const float* __restrict__ gate,
    int M, int Nn, int K, float alpha, int flags)
{
  __shared__ __align__(16) unsigned short As[64*40];
  __shared__ __align__(16) unsigned short Bs[64*40];
  int b = blockIdx.z;
  int m0 = blockIdx.y*64, n0 = blockIdx.x*64;
  const AT* Ab = A + (long)b*sAb;
  const float* Bb = Bm + (long)b*sBb;
  int t = threadIdx.x;
  int w = t >> 6, lane = t & 63, lrowi = lane & 15, lquad = lane >> 4;
  int wm = w >> 1, wn = w & 1;
  f32x4 acc[2][2];
  #pragma unroll
  for (int i = 0; i < 2; i++)
    #pragma unroll
    for (int j = 0; j < 2; j++) acc[i][j] = (f32x4){0.f,0.f,0.f,0.f};

  int am = t >> 2, akq = t & 3;      // A stage: row am, k-offset akq*8

  for (int k0 = 0; k0 < K; k0 += 32){
    // --- stage A (64 x 32) as bf16, LN-affine fused ---
    {
      float av[8];
      const AT* src = Ab + (long)(m0+am)*lda + k0 + akq*8;
      if constexpr (sizeof(AT) == 4){
        const float4* s4 = (const float4*)src;
        float4 u = s4[0], vv = s4[1];
        av[0]=u.x; av[1]=u.y; av[2]=u.z; av[3]=u.w;
        av[4]=vv.x; av[5]=vv.y; av[6]=vv.z; av[7]=vv.w;
      } else {
        uint4 u = *(const uint4*)src;
        const unsigned short* up = (const unsigned short*)&u;
        #pragma unroll
        for (int j = 0; j < 8; j++) av[j] = bf2f(up[j]);
      }
      if (lnG != nullptr){
        #pragma unroll
        for (int j = 0; j < 8; j++) av[j] = fmaf(av[j], lnG[k0+akq*8+j], lnBv[k0+akq*8+j]);
      }
      unsigned short tmp[8];
      #pragma unroll
      for (int j = 0; j < 8; j++) tmp[j] = f2bf(av[j]);
      *(uint4*)(&As[am*40 + akq*8]) = *(uint4*)tmp;
    }
    // --- stage B into Bs[n][k] bf16 ---
    if (flags & FLAG_TRANSB){
      const float* src = Bb + (long)(n0+am)*ldb + k0 + akq*8;
      const float4* s4 = (const float4*)src;
      float4 u = s4[0], vv = s4[1];
      unsigned short tmp[8];
      tmp[0]=f2bf(u.x); tmp[1]=f2bf(u.y); tmp[2]=f2bf(u.z); tmp[3]=f2bf(u.w);
      tmp[4]=f2bf(vv.x); tmp[5]=f2bf(vv.y); tmp[6]=f2bf(vv.z); tmp[7]=f2bf(vv.w);
      *(uint4*)(&Bs[am*40 + akq*8]) = *(uint4*)tmp;
    } else {
      int bn = t & 63, bkb = (t >> 6)*8;
      #pragma unroll
      for (int j = 0; j < 8; j++){
        float vv = Bb[(long)(k0+bkb+j)*ldb + n0 + bn];
        Bs[bn*40 + bkb + j] = f2bf(vv);
      }
    }
    __syncthreads();
    // --- compute ---
    bf16x8 af[2], bfr[2];
    #pragma unroll
    for (int i = 0; i < 2; i++)
      af[i] = *(const bf16x8*)(&As[(wm*32 + i*16 + lrowi)*40 + lquad*8]);
    #pragma unroll
    for (int j = 0; j < 2; j++)
      bfr[j] = *(const bf16x8*)(&Bs[(wn*32 + j*16 + lrowi)*40 + lquad*8]);
    #pragma unroll
    for (int i = 0; i < 2; i++)
      #pragma unroll
      for (int j = 0; j < 2; j++)
        acc[i][j] = __builtin_amdgcn_mfma_f32_16x16x32_bf16(af[i], bfr[j], acc[i][j], 0, 0, 0);
    __syncthreads();
  }
  // --- epilogue ---
  OT* Cb = C + (long)b*sCb;
  const float* Rb = (R != nullptr) ? (R + (long)b*sRb) : nullptr;
  #pragma unroll
  for (int i = 0; i < 2; i++){
    #pragma unroll
    for (int j = 0; j < 2; j++){
      int col = n0 + wn*32 + j*16 + lrowi;
      float bv = (bias != nullptr) ? bias[col] : 0.f;
      float gv = (gate != nullptr) ? gate[col] : 1.f;
      #pragma unroll
      for (int r = 0; r < 4; r++){
        int row = m0 + wm*32 + i*16 + lquad*4 + r;
        float v = alpha*acc[i][j][r];
        v += bv;
        if (flags & FLAG_RELU) v = fmaxf(v, 0.f);
        v *= gv;
        if (Rb != nullptr) v += Rb[(long)row*ldr + col];
        if constexpr (sizeof(OT) == 4) Cb[(long)row*ldc + col] = v;
        else                           Cb[(long)row*ldc + col] = f2bf(v);
      }
    }
  }
}

// ---------------- flash cross-attention (bf16 in/out, f32 online softmax) ----------------
__global__ __launch_bounds__(256) void flash_kernel(
    const unsigned short* __restrict__ Q, const unsigned short* __restrict__ Kt,
    const unsigned short* __restrict__ Vt, unsigned short* __restrict__ O,
    int Nq, int Nk, float scale)
{
  __shared__ __align__(16) unsigned short Kl[32*72];
  __shared__ __align__(16) unsigned short Vl[64*40];
  __shared__ __align__(16) unsigned short Pl[4*16*40];
  int b = blockIdx.z, h = blockIdx.y;
  int t = threadIdx.x, w = t >> 6, lane = t & 63, lrowi = lane & 15, lquad = lane >> 4;
  int q0 = blockIdx.x*64 + w*16;
  const unsigned short* Qb = Q + ((long)b*Nq)*DD + h*DHH;
  const unsigned short* Kb = Kt + ((long)b*Nk)*DD + h*DHH;
  const unsigned short* Vb = Vt + ((long)b*Nk)*DD + h*DHH;
  bf16x8 qa[2];
  #pragma unroll
  for (int kt = 0; kt < 2; kt++)
    qa[kt] = *(const bf16x8*)(Qb + (long)(q0+lrowi)*DD + kt*32 + lquad*8);

  f32x4 o[4];
  #pragma unroll
  for (int cj = 0; cj < 4; cj++) o[cj] = (f32x4){0.f,0.f,0.f,0.f};
  float mrow[4] = {-INFINITY,-INFINITY,-INFINITY,-INFINITY};
  float lsum[4] = {0.f,0.f,0.f,0.f};
  int skq = t >> 3;           // staging key 0..31
  int sdq = (t & 7)*8;        // staging dh offset

  unsigned short* Pw = &Pl[w*16*40];

  for (int kt0 = 0; kt0 < Nk; kt0 += 32){
    // stage K [key][d] and V^T [d][key]
    {
      uint4 kv = *(const uint4*)(Kb + (long)(kt0+skq)*DD + sdq);
      *(uint4*)(&Kl[skq*72 + sdq]) = kv;
      uint4 vv = *(const uint4*)(Vb + (long)(kt0+skq)*DD + sdq);
      const unsigned short* vp = (const unsigned short*)&vv;
      #pragma unroll
      for (int j = 0; j < 8; j++) Vl[(sdq+j)*40 + skq] = vp[j];
    }
    __syncthreads();
    // S = Q @ K^T * scale   (two 16x16 col tiles of 32 keys)
    f32x4 S0 = (f32x4){0.f,0.f,0.f,0.f}, S1 = (f32x4){0.f,0.f,0.f,0.f};
    {
      bf16x8 kb0 = *(const bf16x8*)(&Kl[(0*16+lrowi)*72 + lquad*8]);
      bf16x8 kb1 = *(const bf16x8*)(&Kl[(0*16+lrowi)*72 + 32 + lquad*8]);
      S0 = __builtin_amdgcn_mfma_f32_16x16x32_bf16(qa[0], kb0, S0, 0, 0, 0);
      S0 = __builtin_amdgcn_mfma_f32_16x16x32_bf16(qa[1], kb1, S0, 0, 0, 0);
      bf16x8 kb2 = *(const bf16x8*)(&Kl[(1*16+lrowi)*72 + lquad*8]);
      bf16x8 kb3 = *(const bf16x8*)(&Kl[(1*16+lrowi)*72 + 32 + lquad*8]);
      S1 = __builtin_amdgcn_mfma_f32_16x16x32_bf16(qa[0], kb2, S1, 0, 0, 0);
      S1 = __builtin_amdgcn_mfma_f32_16x16x32_bf16(qa[1], kb3, S1, 0, 0, 0);
    }
    #pragma unroll
    for (int r = 0; r < 4; r++){ S0[r] *= scale; S1[r] *= scale; }
    // online softmax update
    float al[4];
    #pragma unroll
    for (int r = 0; r < 4; r++){
      float m2 = fmaxf(S0[r], S1[r]);
      #pragma unroll
      for (int off = 1; off < 16; off <<= 1) m2 = fmaxf(m2, __shfl_xor(m2, off));
      float mn = fmaxf(mrow[r], m2);
      al[r] = __expf(mrow[r] - mn);
      mrow[r] = mn;
      float p0 = __expf(S0[r]-mn), p1 = __expf(S1[r]-mn);
      S0[r] = p0; S1[r] = p1;
      float s = p0 + p1;
      #pragma unroll
      for (int off = 1; off < 16; off <<= 1) s += __shfl_xor(s, off);
      lsum[r] = lsum[r]*al[r] + s;
    }
    #pragma unroll
    for (int cj = 0; cj < 4; cj++)
      #pragma unroll
      for (int r = 0; r < 4; r++) o[cj][r] *= al[r];
    // P (C-layout) -> LDS -> A-layout frag
    #pragma unroll
    for (int r = 0; r < 4; r++){
      Pw[(lquad*4+r)*40 + lrowi]      = f2bf(S0[r]);
      Pw[(lquad*4+r)*40 + 16 + lrowi] = f2bf(S1[r]);
    }
    __asm__ volatile("s_waitcnt lgkmcnt(0)" ::: "memory");
    bf16x8 pa = *(const bf16x8*)(&Pw[lrowi*40 + lquad*8]);
    #pragma unroll
    for (int cj = 0; cj < 4; cj++){
      bf16x8 vb = *(const bf16x8*)(&Vl[(cj*16+lrowi)*40 + lquad*8]);
      o[cj] = __builtin_amdgcn_mfma_f32_16x16x32_bf16(pa, vb, o[cj], 0, 0, 0);
    }
    __syncthreads();
  }
  // epilogue
  unsigned short* Ob = O + ((long)b*Nq)*DD + h*DHH;
  #pragma unroll
  for (int r = 0; r < 4; r++){
    float rl = 1.f/lsum[r];
    int row = q0 + lquad*4 + r;
    #pragma unroll
    for (int cj = 0; cj < 4; cj++)
      Ob[(long)row*DD + cj*16 + lrowi] = f2bf(o[cj][r]*rl);
  }
}

// ---------------- host ----------------
extern "C" void kernel_launch(void* const* d_in, const int* in_sizes, int n_in,
                              void* d_out, int out_size, void* d_ws, size_t ws_size,
                              hipStream_t stream) {
  (void)in_sizes; (void)n_in; (void)out_size; (void)ws_size;
  const float* x        = (const float*)d_in[0];
  const int*   mask     = (const int*)d_in[1];
  const float* pos_emb  = (const float*)d_in[2];
  const float* sim_p_w  = (const float*)d_in[3];
  const float* sim_p_b  = (const float*)d_in[4];
  const float* sim_n_w  = (const float*)d_in[5];
  const float* sim_n_b  = (const float*)d_in[6];
  const float* adj_w    = (const float*)d_in[7];
  const float* gnn_p_w1 = (const float*)d_in[8];
  const float* gnn_p_w2 = (const float*)d_in[9];
  const float* gnn_n_w1 = (const float*)d_in[10];
  const float* gnn_n_w2 = (const float*)d_in[11];
  const float* ln1_g = (const float*)d_in[12]; const float* ln1_b = (const float*)d_in[13];
  const float* ln2_g = (const float*)d_in[14]; const float* ln2_b = (const float*)d_in[15];
  const float* ln3_g = (const float*)d_in[16]; const float* ln3_b = (const float*)d_in[17];
  const float* ln4_g = (const float*)d_in[18]; const float* ln4_b = (const float*)d_in[19];
  const float* ln5_g = (const float*)d_in[20]; const float* ln5_b = (const float*)d_in[21];
  const float* i2q_wq = (const float*)d_in[22];
  const float* i2q_wk = (const float*)d_in[23];
  const float* i2q_wv = (const float*)d_in[24];
  const float* i2q_wo = (const float*)d_in[25];
  const float* q2i_wq = (const float*)d_in[26];
  const float* q2i_wk = (const float*)d_in[27];
  const float* q2i_wv = (const float*)d_in[28];
  const float* q2i_wo = (const float*)d_in[29];
  const float* i2q_bo = (const float*)d_in[30];
  const float* q2i_bo = (const float*)d_in[31];
  const float* mlp_w  = (const float*)d_in[32];
  const float* mlp_b  = (const float*)d_in[33];
  const float* g_i2t  = (const float*)d_in[34];
  const float* g_t2i  = (const float*)d_in[35];

  float* out  = (float*)d_out;
  float* simP = out + (size_t)BB*NN*DD;
  float* simN = simP + (size_t)BB*NN;

  char* w8 = (char*)d_ws;
  size_t off = 0;
  auto take = [&](size_t bytes)->void*{
    void* p = (void*)(w8 + off);
    off += (bytes + 255) & ~(size_t)255;
    return p;
  };
  float* part   = (float*)take((size_t)BB*32*2*DD*4);
  float* pcnt   = (float*)take((size_t)BB*32*2*4);
  float* posq   = (float*)take((size_t)BB*2*DD*4);
  float* vvec   = (float*)take((size_t)BB*2*DD*4);
  float* cscal  = (float*)take((size_t)BB*2*4);
  int*   idxb   = (int*)take((size_t)BB*2*256*4);
  float* wb     = (float*)take((size_t)BB*2*256*4);
  float* node_p = (float*)take((size_t)BB*KPP*DD*4);
  float* node_n = (float*)take((size_t)BB*KNN*DD*4);
  float* gA     = (float*)take((size_t)BB*256*256*4);
  float* gB     = (float*)take((size_t)BB*256*256*4);
  float* gadj   = (float*)take((size_t)BB*256*256*4);
  float* query  = (float*)take((size_t)BB*384*DD*4);
  float* query2 = (float*)take((size_t)BB*384*DD*4);
  unsigned short* xhatq  = (unsigned short*)take((size_t)BB*384*DD*2);
  unsigned short* qh     = (unsigned short*)take((size_t)BB*384*DD*2);
  unsigned short* attnZ  = (unsigned short*)take((size_t)BB*384*DD*2);
  unsigned short* xhatq2 = (unsigned short*)take((size_t)BB*384*DD*2);
  unsigned short* k2     = (unsigned short*)take((size_t)BB*384*DD*2);
  unsigned short* v2     = (unsigned short*)take((size_t)BB*384*DD*2);
  unsigned short* xhat   = (unsigned short*)take((size_t)BB*NN*DD*2);
  unsigned short* kh     = (unsigned short*)take((size_t)BB*NN*DD*2);
  unsigned short* vh     = (unsigned short*)take((size_t)BB*NN*DD*2);
  float* featb2 = (float*)take((size_t)BB*NN*DD*4);
  // reuse: qh2 <- vh, attn2 <- xhat, xhat5 <- kh (all safely dead at reuse time)
  unsigned short* qh2   = vh;
  unsigned short* attn2 = xhat;
  unsigned short* xhat5 = kh;

  const long sQ  = 384L*DD;   // query batch stride
  const long sX  = (long)NN*DD;
  const long s65 = 65536L;
  const float* NF = nullptr;

  // 1-2: masked means
  stats_part<<<dim3(32, BB), 256, 0, stream>>>(x, mask, part, pcnt);
  stats_final<<<BB, 256, 0, stream>>>(part, pcnt, posq);
  // 3: sim vectors
  sim_vec<<<BB, 256, 0, stream>>>(sim_p_w, sim_p_b, sim_n_w, sim_n_b, posq, vvec, cscal);
  // 4: sims (written straight into d_out)
  sim_kernel<<<dim3(NN/4, BB), 256, 0, stream>>>(x, vvec, cscal, simP, simN);
  // 5: top-k
  topk_kernel<<<dim3(2, BB), 512, 0, stream>>>(simP, simN, idxb, wb);
  // 6: gather nodes
  gather_nodes<<<dim3(KPP+KNN, BB), 256, 0, stream>>>(x, idxb, wb, node_p, node_n);

  // --- GCN pos (K=256) ---
  gemm_kernel<float,float><<<dim3(4,4,BB),256,0,stream>>>(node_p, s65, 256, adj_w, 0, 256,
      gA, s65, 256, NF, 0, 0, NF, NF, NF, NF, 256, 256, 256, 1.f, 0);
  gemm_kernel<float,float><<<dim3(4,4,BB),256,0,stream>>>(gA, s65, 256, node_p, s65, 256,
      gadj, s65, 256, NF, 0, 0, NF, NF, NF, NF, 256, 256, 256, 0.0625f, FLAG_TRANSB);
  softmax_rows<<<BB*256/4, 256, 0, stream>>>(gadj, 256, 256, s65, BB*256);
  gemm_kernel<float,float><<<dim3(4,4,BB),256,0,stream>>>(node_p, s65, 256, gnn_p_w1, 0, 256,
      gA, s65, 256, NF, 0, 0, NF, NF, NF, NF, 256, 256, 256, 1.f, 0);
  gemm_kernel<float,float><<<dim3(4,4,BB),256,0,stream>>>(gadj, s65, 256, gA, s65, 256,
      gB, s65, 256, NF, 0, 0, NF, NF, NF, NF, 256, 256, 256, 1.f, FLAG_RELU);
  gemm_kernel<float,float><<<dim3(4,4,BB),256,0,stream>>>(gB, s65, 256, gnn_p_w2, 0, 256,
      gA, s65, 256, NF, 0, 0, NF, NF, NF, NF, 256, 256, 256, 1.f, 0);
  gemm_kernel<float,float><<<dim3(4,4,BB),256,0,stream>>>(gadj, s65, 256, gA, s65, 256,
      query, sQ, 256, NF, 0, 0, NF, NF, NF, NF, 256, 256, 256, 1.f, 0);
  // --- GCN neg (M=N=128) ---
  gemm_kernel<float,float><<<dim3(4,2,BB),256,0,stream>>>(node_n, 32768L, 256, adj_w, 0, 256,
      gA, s65, 256, NF, 0, 0, NF, NF, NF, NF, 128, 256, 256, 1.f, 0);
  gemm_kernel<float,float><<<dim3(2,2,BB),256,0,stream>>>(gA, s65, 256, node_n, 32768L, 256,
      gadj, s65, 128, NF, 0, 0, NF, NF, NF, NF, 128, 128, 256, 0.0625f, FLAG_TRANSB);
  softmax_rows<<<BB*128/4, 256, 0, stream>>>(gadj, 128, 128, s65, BB*128);
  gemm_kernel<float,float><<<dim3(4,2,BB),256,0,stream>>>(node_n, 32768L, 256, gnn_n_w1, 0, 256,
      gA, s65, 256, NF, 0, 0, NF, NF, NF, NF, 128, 256, 256, 1.f, 0);
  gemm_kernel<float,float><<<dim3(4,2,BB),256,0,stream>>>(gadj, s65, 128, gA, s65, 256,
      gB, s65, 256, NF, 0, 0, NF, NF, NF, NF, 128, 256, 128, 1.f, FLAG_RELU);
  gemm_kernel<float,float><<<dim3(4,2,BB),256,0,stream>>>(gB, s65, 256, gnn_n_w2, 0, 256,
      gA, s65, 256, NF, 0, 0, NF, NF, NF, NF, 128, 256, 256, 1.f, 0);
  gemm_kernel<float,float><<<dim3(4,2,BB),256,0,stream>>>(gadj, s65, 128, gA, s65, 256,
      query + 256L*DD, sQ, 256, NF, 0, 0, NF, NF, NF, NF, 128, 256, 128, 1.f, 0);
  // query += pos_emb[idx]
  add_posemb<<<dim3(384, BB), 256, 0, stream>>>(query, idxb, pos_emb);

  // --- LN cores ---
  rownorm_kernel<<<BB*NN/4, 256, 0, stream>>>(x, xhat, BB*NN);
  rownorm_kernel<<<BB*384/4, 256, 0, stream>>>(query, xhatq, BB*384);

  // --- i2q projections ---
  gemm_kernel<unsigned short,unsigned short><<<dim3(4,6,BB),256,0,stream>>>(xhatq, sQ, 256,
      i2q_wq, 0, 256, qh, sQ, 256, NF, 0, 0, ln1_g, ln1_b, NF, NF, 384, 256, 256, 1.f, 0);
  gemm_kernel<unsigned short,unsigned short><<<dim3(4,64,BB),256,0,stream>>>(xhat, sX, 256,
      i2q_wk, 0, 256, kh, sX, 256, NF, 0, 0, ln2_g, ln2_b, NF, NF, NN, 256, 256, 1.f, 0);
  gemm_kernel<unsigned short,unsigned short><<<dim3(4,64,BB),256,0,stream>>>(xhat, sX, 256,
      i2q_wv, 0, 256, vh, sX, 256, NF, 0, 0, ln2_g, ln2_b, NF, NF, NN, 256, 256, 1.f, 0);
  // --- i2q attention ---
  flash_kernel<<<dim3(384/64, HH, BB), 256, 0, stream>>>(qh, kh, vh, attnZ, 384, NN, 0.125f);
  // query2 = query + g_i2t .* (attnZ @ wo + bo)
  gemm_kernel<unsigned short,float><<<dim3(4,6,BB),256,0,stream>>>(attnZ, sQ, 256,
      i2q_wo, 0, 256, query2, sQ, 256, query, sQ, 256, NF, NF, i2q_bo, g_i2t,
      384, 256, 256, 1.f, 0);

  // --- q2i projections ---
  rownorm_kernel<<<BB*384/4, 256, 0, stream>>>(query2, xhatq2, BB*384);
  gemm_kernel<unsigned short,unsigned short><<<dim3(4,64,BB),256,0,stream>>>(xhat, sX, 256,
      q2i_wq, 0, 256, qh2, sX, 256, NF, 0, 0, ln3_g, ln3_b, NF, NF, NN, 256, 256, 1.f, 0);
  gemm_kernel<unsigned short,unsigned short><<<dim3(4,6,BB),256,0,stream>>>(xhatq2, sQ, 256,
      q2i_wk, 0, 256, k2, sQ, 256, NF, 0, 0, ln4_g, ln4_b, NF, NF, 384, 256, 256, 1.f, 0);
  gemm_kernel<unsigned short,unsigned short><<<dim3(4,6,BB),256,0,stream>>>(xhatq2, sQ, 256,
      q2i_wv, 0, 256, v2, sQ, 256, NF, 0, 0, ln4_g, ln4_b, NF, NF, 384, 256, 256, 1.f, 0);
  // --- q2i attention ---
  flash_kernel<<<dim3(NN/64, HH, BB), 256, 0, stream>>>(qh2, k2, v2, attn2, NN, 384, 0.125f);
  // featb2 = x + g_t2i .* (attn2 @ wo + bo)
  gemm_kernel<unsigned short,float><<<dim3(4,64,BB),256,0,stream>>>(attn2, sX, 256,
      q2i_wo, 0, 256, featb2, sX, 256, x, sX, 256, NF, NF, q2i_bo, g_t2i,
      NN, 256, 256, 1.f, 0);

  // --- final MLP ---
  rownorm_kernel<<<BB*NN/4, 256, 0, stream>>>(featb2, xhat5, BB*NN);
  gemm_kernel<unsigned short,float><<<dim3(4,64,BB),256,0,stream>>>(xhat5, sX, 256,
      mlp_w, 0, 256, out, sX, 256, featb2, sX, 256, ln5_g, ln5_b, mlp_b, NF,
      NN, 256, 256, 1.f, 0);
}

// Round 2
// 689.000 us; speedup vs baseline: 1.3393x; 1.3393x over previous
//
#include <hip/hip_runtime.h>

#define BB 8
#define NN 4096
#define DD 256
#define HH 4
#define DHH 64
#define KPP 256
#define KNN 128

typedef float f32x4 __attribute__((ext_vector_type(4)));
typedef short bf16x8 __attribute__((ext_vector_type(8)));

#define FLAG_TRANSB 1
#define FLAG_RELU   2

__device__ __forceinline__ float bf2f(unsigned short u){
  union { unsigned int i; float f; } v; v.i = ((unsigned int)u) << 16; return v.f;
}
__device__ __forceinline__ unsigned short f2bf(float f){
  union { float f; unsigned int i; } v; v.f = f;
  return (unsigned short)((v.i + 0x7FFFu + ((v.i >> 16) & 1u)) >> 16);
}
__device__ __forceinline__ void gload16(const void* g, void* l){
  __builtin_amdgcn_global_load_lds((const __attribute__((address_space(1))) void*)g,
                                   (__attribute__((address_space(3))) void*)l, 16, 0, 0);
}

// ---------------- masked-mean stats (2-stage) ----------------
__global__ void stats_part(const float* __restrict__ x, const int* __restrict__ mask,
                           float* __restrict__ part, float* __restrict__ pcnt){
  int b = blockIdx.y, c = blockIdx.x, d = threadIdx.x;
  int n0 = c * 128;
  float sp = 0.f, sn = 0.f; int cp = 0, cn = 0;
  const float* xb = x + ((long)b*NN + n0)*DD + d;
  const int* mb = mask + (long)b*NN + n0;
  for (int r = 0; r < 128; r++){
    int mv = mb[r];
    float v = xb[(long)r*DD];
    if (mv == 1){ sp += v; cp++; }
    else if (mv == -1){ sn += v; cn++; }
  }
  part[(((long)(b*32+c)*2+0)*DD)+d] = sp;
  part[(((long)(b*32+c)*2+1)*DD)+d] = sn;
  if (d == 0){ pcnt[(b*32+c)*2+0] = (float)cp; pcnt[(b*32+c)*2+1] = (float)cn; }
}

__global__ void stats_final(const float* __restrict__ part, const float* __restrict__ pcnt,
                            float* __restrict__ posq){
  int b = blockIdx.x, d = threadIdx.x;
  float sp=0.f, sn=0.f, cp=0.f, cn=0.f;
  for (int c = 0; c < 32; c++){
    sp += part[(((long)(b*32+c)*2+0)*DD)+d];
    sn += part[(((long)(b*32+c)*2+1)*DD)+d];
    cp += pcnt[(b*32+c)*2+0];
    cn += pcnt[(b*32+c)*2+1];
  }
  posq[(long)(b*2+0)*DD + d] = sp / (cp + 1e-6f);
  posq[(long)(b*2+1)*DD + d] = sn / (cn + 1e-6f);
}

// ---------------- sim vectors: v = W @ q, c = b . q ----------------
__global__ void sim_vec(const float* __restrict__ Wp, const float* __restrict__ bp,
                        const float* __restrict__ Wn, const float* __restrict__ bn,
                        const float* __restrict__ posq, float* __restrict__ vvec,
                        float* __restrict__ cscal){
  int b = blockIdx.x, k = threadIdx.x;
  const float* qp = posq + (long)(b*2+0)*DD;
  const float* qn = posq + (long)(b*2+1)*DD;
  float vp = 0.f, vn = 0.f;
  for (int j = 0; j < DD; j++){ vp += Wp[(long)k*DD+j]*qp[j]; vn += Wn[(long)k*DD+j]*qn[j]; }
  vvec[(long)(b*2+0)*DD+k] = vp; vvec[(long)(b*2+1)*DD+k] = vn;
  __shared__ float red[256];
  red[k] = bp[k]*qp[k];
  __syncthreads();
  for (int s = 128; s > 0; s >>= 1){ if (k < s) red[k] += red[k+s]; __syncthreads(); }
  if (k == 0) cscal[b*2+0] = red[0];
  __syncthreads();
  red[k] = bn[k]*qn[k];
  __syncthreads();
  for (int s = 128; s > 0; s >>= 1){ if (k < s) red[k] += red[k+s]; __syncthreads(); }
  if (k == 0) cscal[b*2+1] = red[0];
}

// ---------------- sims: sigmoid(x . v + c) ----------------
__global__ void sim_kernel(const float* __restrict__ x, const float* __restrict__ vvec,
                           const float* __restrict__ cscal,
                           float* __restrict__ simP, float* __restrict__ simN){
  int b = blockIdx.y;
  int w = threadIdx.x >> 6, lane = threadIdx.x & 63;
  int n = blockIdx.x*4 + w;
  const float4* xr = (const float4*)(x + ((long)b*NN + n)*DD);
  const float4* vp = (const float4*)(vvec + (long)(b*2+0)*DD);
  const float4* vn = (const float4*)(vvec + (long)(b*2+1)*DD);
  float4 xv = xr[lane];
  float4 a = vp[lane], c = vn[lane];
  float sp = xv.x*a.x + xv.y*a.y + xv.z*a.z + xv.w*a.w;
  float sn = xv.x*c.x + xv.y*c.y + xv.z*c.z + xv.w*c.w;
  for (int off = 32; off; off >>= 1){ sp += __shfl_xor(sp, off); sn += __shfl_xor(sn, off); }
  if (lane == 0){
    float zp = sp + cscal[b*2+0], zn = sn + cscal[b*2+1];
    simP[(long)b*NN+n] = 1.f/(1.f+expf(-zp));
    simN[(long)b*NN+n] = 1.f/(1.f+expf(-zn));
  }
}

// ---------------- per-batch top-k via bitonic sort ----------------
__global__ __launch_bounds__(512) void topk_kernel(const float* __restrict__ simP,
                                                   const float* __restrict__ simN,
                                                   int* __restrict__ idxb, float* __restrict__ wb){
  __shared__ float v[4096];
  __shared__ int ix[4096];
  int sgn = blockIdx.x, b = blockIdx.y, t = threadIdx.x;
  const float* s = (sgn == 0 ? simP : simN) + (long)b*NN;
  for (int i = t; i < 4096; i += 512){ v[i] = s[i]; ix[i] = i; }
  __syncthreads();
  for (int k = 2; k <= 4096; k <<= 1){
    for (int j = k >> 1; j > 0; j >>= 1){
      for (int i = t; i < 4096; i += 512){
        int l = i ^ j;
        if (l > i){
          bool dir = ((i & k) == 0);
          float va = v[i], vb = v[l]; int ia = ix[i], ib = ix[l];
          bool g = (va > vb) || (va == vb && ia < ib);
          if (g != dir){ v[i] = vb; v[l] = va; ix[i] = ib; ix[l] = ia; }
        }
      }
      __syncthreads();
    }
  }
  int K = (sgn == 0) ? KPP : KNN;
  for (int i = t; i < K; i += 512){
    idxb[(long)(b*2+sgn)*256+i] = ix[i];
    wb[(long)(b*2+sgn)*256+i] = v[i];
  }
}

// ---------------- gather masked nodes (stacked pos 0-255, neg 256-383) ----------------
__global__ void gather_nodes(const float* __restrict__ x, const int* __restrict__ idxb,
                             const float* __restrict__ wb, float* __restrict__ node){
  int b = blockIdx.y, i = blockIdx.x, d = threadIdx.x;
  int sgn = (i < KPP) ? 0 : 1;
  int ii = (sgn == 0) ? i : i - KPP;
  int idx = idxb[(long)(b*2+sgn)*256+ii];
  float w = wb[(long)(b*2+sgn)*256+ii];
  float val = (w > 0.6f) ? x[((long)b*NN + idx)*DD + d] : 0.f;
  node[((long)b*384 + i)*DD + d] = val;
}

// ---------------- dual row softmax ----------------
__global__ void softmax_dual(float* __restrict__ A0, int L0, int rpb0, long bs0, int rows0,
                             float* __restrict__ A1, int L1, int rpb1, long bs1, int rows1){
  int w = threadIdx.x >> 6, lane = threadIdx.x & 63;
  long row = (long)blockIdx.x*4 + w;
  float* A; int L, rpb; long bs;
  if (row < rows0){ A = A0; L = L0; rpb = rpb0; bs = bs0; }
  else { row -= rows0; if (row >= rows1) return; A = A1; L = L1; rpb = rpb1; bs = bs1; }
  int b = (int)(row / rpb), r = (int)(row % rpb);
  float* a = A + (long)b*bs + (long)r*L;
  int e = L >> 6;
  float vals[4]; float mx = -1e30f;
  for (int j = 0; j < e; j++){ vals[j] = a[lane*e+j]; mx = fmaxf(mx, vals[j]); }
  for (int off = 32; off; off >>= 1) mx = fmaxf(mx, __shfl_xor(mx, off));
  float sum = 0.f;
  for (int j = 0; j < e; j++){ vals[j] = expf(vals[j]-mx); sum += vals[j]; }
  for (int off = 32; off; off >>= 1) sum += __shfl_xor(sum, off);
  float rinv = 1.f/sum;
  for (int j = 0; j < e; j++) a[lane*e+j] = vals[j]*rinv;
}

// ---------------- add gathered pos_emb to query ----------------
__global__ void add_posemb(float* __restrict__ query, const int* __restrict__ idxb,
                           const float* __restrict__ pe){
  int b = blockIdx.y, i = blockIdx.x, d = threadIdx.x;
  int sgn = (i < KPP) ? 0 : 1;
  int ii = (sgn == 0) ? i : i - KPP;
  int idx = idxb[(long)(b*2+sgn)*256+ii];
  query[((long)b*384+i)*DD + d] += pe[(long)idx*DD + d];
}

// ---------------- row LayerNorm core (no affine) f32 -> bf16 ----------------
__global__ void rownorm_kernel(const float* __restrict__ X, unsigned short* __restrict__ Y, int rows){
  int w = threadIdx.x >> 6, lane = threadIdx.x & 63;
  long row = (long)blockIdx.x*4 + w;
  if (row >= rows) return;
  const float4* xr = (const float4*)(X + row*DD);
  float4 xv = xr[lane];
  float s = xv.x+xv.y+xv.z+xv.w;
  float q = xv.x*xv.x+xv.y*xv.y+xv.z*xv.z+xv.w*xv.w;
  for (int off = 32; off; off >>= 1){ s += __shfl_xor(s, off); q += __shfl_xor(q, off); }
  float m = s*(1.f/256.f);
  float var = q*(1.f/256.f) - m*m;
  float rinv = rsqrtf(var + 1e-5f);
  ushort4 o;
  o.x = f2bf((xv.x-m)*rinv); o.y = f2bf((xv.y-m)*rinv);
  o.z = f2bf((xv.z-m)*rinv); o.w = f2bf((xv.w-m)*rinv);
  ((ushort4*)(Y + row*DD))[lane] = o;
}

// ---------------- weight fold: BT[n][k] = g[k]*W[k][n] (bf16) ----------------
struct FoldArgs { const float* W[9]; const float* g[9]; unsigned short* BT[9]; };
struct BiasArgs { const float* W[7]; const float* b[7]; const float* addb[7]; float* out[7]; };

__global__ void fold_w(FoldArgs fa){
  int m = blockIdx.y, tile = blockIdx.x, t = threadIdx.x;
  const float* W = fa.W[m]; const float* g = fa.g[m]; unsigned short* BT = fa.BT[m];
  __shared__ float T[64][65];
  int tn = (tile & 3)*64, tk = (tile >> 2)*64;
  #pragma unroll 4
  for (int p = 0; p < 16; p++){
    int kl = p*4 + (t >> 6), nl = t & 63;
    float v = W[(long)(tk+kl)*256 + tn + nl];
    if (g) v *= g[tk+kl];
    T[kl][nl] = v;
  }
  __syncthreads();
  #pragma unroll 4
  for (int p = 0; p < 16; p++){
    int nl = p*4 + (t >> 6), kl = t & 63;
    BT[(long)(tn+nl)*256 + tk + kl] = f2bf(T[kl][nl]);
  }
}

__global__ void fold_b(BiasArgs ba){
  int m = blockIdx.x, n = threadIdx.x;
  const float* W = ba.W[m]; const float* b = ba.b[m];
  float s = (ba.addb[m] != nullptr) ? ba.addb[m][n] : 0.f;
  for (int k = 0; k < 256; k++) s += b[k]*W[(long)k*256+n];
  ba.out[m][n] = s;
}

// ---------------- dual-parameter f32 GEMM 64x64 (GCN path) ----------------
struct GP {
  const float* A; long sAb; int lda;
  const float* B; long sBb; int ldb;
  float* C; long sCb; int ldc;
  int M, N, K; float alpha; int flags;
};

__global__ __launch_bounds__(256) void gemm_dual(GP p0, GP p1){
  GP p = (blockIdx.z < BB) ? p0 : p1;
  int b = blockIdx.z & (BB-1);
  int m0 = blockIdx.y*64, n0 = blockIdx.x*64;
  if (m0 >= p.M || n0 >= p.N) return;
  __shared__ __align__(16) unsigned short As[64*40];
  __shared__ __align__(16) unsigned short Bs[64*40];
  const float* Ab = p.A + (long)b*p.sAb;
  const float* Bb = p.B + (long)b*p.sBb;
  int t = threadIdx.x;
  int w = t >> 6, lane = t & 63, lrowi = lane & 15, lquad = lane >> 4;
  int wm = w >> 1, wn = w & 1;
  f32x4 acc[2][2];
  #pragma unroll
  for (int i = 0; i < 2; i++)
    #pragma unroll
    for (int j = 0; j < 2; j++) acc[i][j] = (f32x4){0.f,0.f,0.f,0.f};
  int am = t >> 2, akq = t & 3;
  for (int k0 = 0; k0 < p.K; k0 += 32){
    {
      const float4* s4 = (const float4*)(Ab + (long)(m0+am)*p.lda + k0 + akq*8);
      float4 u = s4[0], vv = s4[1];
      unsigned short tmp[8];
      tmp[0]=f2bf(u.x); tmp[1]=f2bf(u.y); tmp[2]=f2bf(u.z); tmp[3]=f2bf(u.w);
      tmp[4]=f2bf(vv.x); tmp[5]=f2bf(vv.y); tmp[6]=f2bf(vv.z); tmp[7]=f2bf(vv.w);
      *(uint4*)(&As[am*40 + akq*8]) = *(uint4*)tmp;
    }
    if (p.flags & FLAG_TRANSB){
      const float4* s4 = (const float4*)(Bb + (long)(n0+am)*p.ldb + k0 + akq*8);
      float4 u = s4[0], vv = s4[1];
      unsigned short tmp[8];
      tmp[0]=f2bf(u.x); tmp[1]=f2bf(u.y); tmp[2]=f2bf(u.z); tmp[3]=f2bf(u.w);
      tmp[4]=f2bf(vv.x); tmp[5]=f2bf(vv.y); tmp[6]=f2bf(vv.z); tmp[7]=f2bf(vv.w);
      *(uint4*)(&Bs[am*40 + akq*8]) = *(uint4*)tmp;
    } else {
      int bn = t & 63, bkb = (t >> 6)*8;
      #pragma unroll
      for (int j = 0; j < 8; j++)
        Bs[bn*40 + bkb + j] = f2bf(Bb[(long)(k0+bkb+j)*p.ldb + n0 + bn]);
    }
    __syncthreads();
    bf16x8 af[2], bfr[2];
    #pragma unroll
    for (int i = 0; i < 2; i++)
      af[i] = *(const bf16x8*)(&As[(wm*32 + i*16 + lrowi)*40 + lquad*8]);
    #pragma unroll
    for (int j = 0; j < 2; j++)
      bfr[j] = *(const bf16x8*)(&Bs[(wn*32 + j*16 + lrowi)*40 + lquad*8]);
    #pragma unroll
    for (int i = 0; i < 2; i++)
      #pragma unroll
      for (int j = 0; j < 2; j++)
        acc[i][j] = __builtin_amdgcn_mfma_f32_16x16x32_bf16(af[i], bfr[j], acc[i][j], 0, 0, 0);
    __syncthreads();
  }
  float* Cb = p.C + (long)b*p.sCb;
  #pragma unroll
  for (int i = 0; i < 2; i++)
    #pragma unroll
    for (int j = 0; j < 2; j++){
      int col = n0 + wn*32 + j*16 + lrowi;
      #pragma unroll
      for (int r = 0; r < 4; r++){
        int row = m0 + wm*32 + i*16 + lquad*4 + r;
        float v = p.alpha*acc[i][j][r];
        if (p.flags & FLAG_RELU) v = fmaxf(v, 0.f);
        Cb[(long)row*p.ldc + col] = v;
      }
    }
}

// ---------------- fast 128x128 bf16 GEMM (K=256), global_load_lds staging ----------------
// C = R + gate .* (A @ BT^T + bias)
template<typename OT, bool RES, bool GATE>
__global__ __launch_bounds__(256) void gemm128(
    const unsigned short* __restrict__ A, long sAb,
    const unsigned short* __restrict__ BT,
    OT* __restrict__ C, long sCb, int ldc,
    const float* __restrict__ R, long sRb,
    const float* __restrict__ bias, const float* __restrict__ gate)
{
  __shared__ __align__(16) unsigned short As[4096];
  __shared__ __align__(16) unsigned short Bs[4096];
  int t = threadIdx.x;
  int w = t >> 6, lane = t & 63, lrowi = lane & 15, lquad = lane >> 4;
  int wm = w >> 1, wn = w & 1;
  int m0 = blockIdx.y*128, n0 = blockIdx.x*128;
  const unsigned short* Ab = A + (long)blockIdx.z*sAb + (long)m0*256;
  const unsigned short* Bb = BT + (long)n0*256;
  int g0 = t, g1 = 256 + t;
  int row0 = g0 >> 2, kq0 = g0 & 3;
  int row1 = g1 >> 2, kq1 = g1 & 3;
  f32x4 acc[4][4];
  #pragma unroll
  for (int i = 0; i < 4; i++)
    #pragma unroll
    for (int j = 0; j < 4; j++) acc[i][j] = (f32x4){0.f,0.f,0.f,0.f};

  for (int k0 = 0; k0 < 256; k0 += 32){
    gload16(Ab + (long)row0*256 + k0 + kq0*8, &As[g0*8]);
    gload16(Ab + (long)row1*256 + k0 + kq1*8, &As[g1*8]);
    gload16(Bb + (long)row0*256 + k0 + kq0*8, &Bs[g0*8]);
    gload16(Bb + (long)row1*256 + k0 + kq1*8, &Bs[g1*8]);
    __syncthreads();
    bf16x8 af[4], bfr[4];
    #pragma unroll
    for (int i = 0; i < 4; i++)
      af[i] = *(const bf16x8*)(&As[((wm*64 + i*16 + lrowi)*4 + lquad)*8]);
    #pragma unroll
    for (int j = 0; j < 4; j++)
      bfr[j] = *(const bf16x8*)(&Bs[((wn*64 + j*16 + lrowi)*4 + lquad)*8]);
    #pragma unroll
    for (int i = 0; i < 4; i++)
      #pragma unroll
      for (int j = 0; j < 4; j++)
        acc[i][j] = __builtin_amdgcn_mfma_f32_16x16x32_bf16(af[i], bfr[j], acc[i][j], 0, 0, 0);
    __syncthreads();
  }
  OT* Cb = C + (long)blockIdx.z*sCb;
  const float* Rb = RES ? (R + (long)blockIdx.z*sRb) : nullptr;
  #pragma unroll
  for (int j = 0; j < 4; j++){
    int col = n0 + wn*64 + j*16 + lrowi;
    float bv = bias[col];
    float gv = GATE ? gate[col] : 1.f;
    #pragma unroll
    for (int i = 0; i < 4; i++){
      #pragma unroll
      for (int r = 0; r < 4; r++){
        int row = m0 + wm*64 + i*16 + lquad*4 + r;
        float v = acc[i][j][r] + bv;
        if (GATE) v *= gv;
        if (RES) v += Rb[(long)row*256 + col];
        if constexpr (sizeof(OT) == 4) Cb[(long)row*ldc + col] = v;
        else                           Cb[(long)row*ldc + col] = f2bf(v);
      }
    }
  }
}

// ---------------- flash cross-attention with optional K-split ----------------
__global__ __launch_bounds__(256) void flash_kernel(
    const unsigned short* __restrict__ Q, long sQb, int ldq,
    const unsigned short* __restrict__ Kt, const unsigned short* __restrict__ Vt,
    long sKb, int ldkv,
    unsigned short* __restrict__ O, long sOb,
    float* __restrict__ Opart, float* __restrict__ Mpart, float* __restrict__ Lpart,
    int Nq, int Nk, int nsplit, float scale)
{
  __shared__ __align__(16) unsigned short Kl[32*72];
  __shared__ __align__(16) unsigned short Vl[64*40];
  __shared__ __align__(16) unsigned short Pl[4*16*40];
  int b = blockIdx.z, h = blockIdx.y;
  int nqt = Nq >> 6;
  int qtile = blockIdx.x % nqt, split = blockIdx.x / nqt;
  int kchunk = Nk / nsplit;
  int kbeg = split*kchunk, kend = kbeg + kchunk;
  int t = threadIdx.x, w = t >> 6, lane = t & 63, lrowi = lane & 15, lquad = lane >> 4;
  int q0 = qtile*64 + w*16;
  const unsigned short* Qb = Q + (long)b*sQb + h*DHH;
  const unsigned short* Kb = Kt + (long)b*sKb + h*DHH;
  const unsigned short* Vb = Vt + (long)b*sKb + h*DHH;
  bf16x8 qa[2];
  #pragma unroll
  for (int kt = 0; kt < 2; kt++)
    qa[kt] = *(const bf16x8*)(Qb + (long)(q0+lrowi)*ldq + kt*32 + lquad*8);

  f32x4 o[4];
  #pragma unroll
  for (int cj = 0; cj < 4; cj++) o[cj] = (f32x4){0.f,0.f,0.f,0.f};
  float mrow[4] = {-INFINITY,-INFINITY,-INFINITY,-INFINITY};
  float lsum[4] = {0.f,0.f,0.f,0.f};
  int skq = t >> 3;
  int sdq = (t & 7)*8;
  unsigned short* Pw = &Pl[w*16*40];

  for (int kt0 = kbeg; kt0 < kend; kt0 += 32){
    {
      uint4 kv = *(const uint4*)(Kb + (long)(kt0+skq)*ldkv + sdq);
      *(uint4*)(&Kl[skq*72 + sdq]) = kv;
      uint4 vv = *(const uint4*)(Vb + (long)(kt0+skq)*ldkv + sdq);
      const unsigned short* vp = (const unsigned short*)&vv;
      #pragma unroll
      for (int j = 0; j < 8; j++) Vl[(sdq+j)*40 + skq] = vp[j];
    }
    __syncthreads();
    f32x4 S0 = (f32x4){0.f,0.f,0.f,0.f}, S1 = (f32x4){0.f,0.f,0.f,0.f};
    {
      bf16x8 kb0 = *(const bf16x8*)(&Kl[(0*16+lrowi)*72 + lquad*8]);
      bf16x8 kb1 = *(const bf16x8*)(&Kl[(0*16+lrowi)*72 + 32 + lquad*8]);
      S0 = __builtin_amdgcn_mfma_f32_16x16x32_bf16(qa[0], kb0, S0, 0, 0, 0);
      S0 = __builtin_amdgcn_mfma_f32_16x16x32_bf16(qa[1], kb1, S0, 0, 0, 0);
      bf16x8 kb2 = *(const bf16x8*)(&Kl[(1*16+lrowi)*72 + lquad*8]);
      bf16x8 kb3 = *(const bf16x8*)(&Kl[(1*16+lrowi)*72 + 32 + lquad*8]);
      S1 = __builtin_amdgcn_mfma_f32_16x16x32_bf16(qa[0], kb2, S1, 0, 0, 0);
      S1 = __builtin_amdgcn_mfma_f32_16x16x32_bf16(qa[1], kb3, S1, 0, 0, 0);
    }
    #pragma unroll
    for (int r = 0; r < 4; r++){ S0[r] *= scale; S1[r] *= scale; }
    float al[4];
    #pragma unroll
    for (int r = 0; r < 4; r++){
      float m2 = fmaxf(S0[r], S1[r]);
      #pragma unroll
      for (int off = 1; off < 16; off <<= 1) m2 = fmaxf(m2, __shfl_xor(m2, off));
      float mn = fmaxf(mrow[r], m2);
      al[r] = __expf(mrow[r] - mn);
      mrow[r] = mn;
      float p0 = __expf(S0[r]-mn), p1 = __expf(S1[r]-mn);
      S0[r] = p0; S1[r] = p1;
      float s = p0 + p1;
      #pragma unroll
      for (int off = 1; off < 16; off <<= 1) s += __shfl_xor(s, off);
      lsum[r] = lsum[r]*al[r] + s;
    }
    #pragma unroll
    for (int cj = 0; cj < 4; cj++)
      #pragma unroll
      for (int r = 0; r < 4; r++) o[cj][r] *= al[r];
    #pragma unroll
    for (int r = 0; r < 4; r++){
      Pw[(lquad*4+r)*40 + lrowi]      = f2bf(S0[r]);
      Pw[(lquad*4+r)*40 + 16 + lrowi] = f2bf(S1[r]);
    }
    __asm__ volatile("s_waitcnt lgkmcnt(0)" ::: "memory");
    bf16x8 pa = *(const bf16x8*)(&Pw[lrowi*40 + lquad*8]);
    #pragma unroll
    for (int cj = 0; cj < 4; cj++){
      bf16x8 vb = *(const bf16x8*)(&Vl[(cj*16+lrowi)*40 + lquad*8]);
      o[cj] = __builtin_amdgcn_mfma_f32_16x16x32_bf16(pa, vb, o[cj], 0, 0, 0);
    }
    __syncthreads();
  }
  if (nsplit > 1){
    int p = (b*HH + h)*nsplit + split;
    float* Op = Opart + (long)p*Nq*DHH;
    #pragma unroll
    for (int r = 0; r < 4; r++){
      int row = q0 + lquad*4 + r;
      #pragma unroll
      for (int cj = 0; cj < 4; cj++)
        Op[(long)row*DHH + cj*16 + lrowi] = o[cj][r];
      if (lrowi == 0){
        Mpart[(long)p*Nq + row] = mrow[r];
        Lpart[(long)p*Nq + row] = lsum[r];
      }
    }
  } else {
    unsigned short* Ob = O + (long)b*sOb + h*DHH;
    #pragma unroll
    for (int r = 0; r < 4; r++){
      float rl = 1.f/lsum[r];
      int row = q0 + lquad*4 + r;
      #pragma unroll
      for (int cj = 0; cj < 4; cj++)
        Ob[(long)row*DD + cj*16 + lrowi] = f2bf(o[cj][r]*rl);
    }
  }
}

// ---------------- flash split combine ----------------
__global__ void flash_combine(const float* __restrict__ Opart, const float* __restrict__ Mpart,
                              const float* __restrict__ Lpart, unsigned short* __restrict__ O,
                              long sOb, int Nq, int nsplit){
  int gr = blockIdx.x*4 + (threadIdx.x >> 6);
  int d = threadIdx.x & 63;
  int bh = gr / Nq, row = gr % Nq;
  float M = -INFINITY;
  for (int s = 0; s < nsplit; s++)
    M = fmaxf(M, Mpart[((long)bh*nsplit + s)*Nq + row]);
  float accO = 0.f, accL = 0.f;
  for (int s = 0; s < nsplit; s++){
    long p = (long)bh*nsplit + s;
    float wv = __expf(Mpart[p*Nq + row] - M);
    accL += wv*Lpart[p*Nq + row];
    accO += wv*Opart[(p*Nq + row)*DHH + d];
  }
  int b = bh / HH, h = bh % HH;
  O[(long)b*sOb + (long)row*DD + h*DHH + d] = f2bf(accO/accL);
}

// ---------------- host ----------------
extern "C" void kernel_launch(void* const* d_in, const int* in_sizes, int n_in,
                              void* d_out, int out_size, void* d_ws, size_t ws_size,
                              hipStream_t stream) {
  (void)in_sizes; (void)n_in; (void)out_size; (void)ws_size;
  const float* x        = (const float*)d_in[0];
  const int*   mask     = (const int*)d_in[1];
  const float* pos_emb  = (const float*)d_in[2];
  const float* sim_p_w  = (const float*)d_in[3];
  const float* sim_p_b  = (const float*)d_in[4];
  const float* sim_n_w  = (const float*)d_in[5];
  const float* sim_n_b  = (const float*)d_in[6];
  const float* adj_w    = (const float*)d_in[7];
  const float* gnn_p_w1 = (const float*)d_in[8];
  const float* gnn_p_w2 = (const float*)d_in[9];
  const float* gnn_n_w1 = (const float*)d_in[10];
  const float* gnn_n_w2 = (const float*)d_in[11];
  const float* ln1_g = (const float*)d_in[12]; const float* ln1_b = (const float*)d_in[13];
  const float* ln2_g = (const float*)d_in[14]; const float* ln2_b = (const float*)d_in[15];
  const float* ln3_g = (const float*)d_in[16]; const float* ln3_b = (const float*)d_in[17];
  const float* ln4_g = (const float*)d_in[18]; const float* ln4_b = (const float*)d_in[19];
  const float* ln5_g = (const float*)d_in[20]; const float* ln5_b = (const float*)d_in[21];
  const float* i2q_wq = (const float*)d_in[22];
  const float* i2q_wk = (const float*)d_in[23];
  const float* i2q_wv = (const float*)d_in[24];
  const float* i2q_wo = (const float*)d_in[25];
  const float* q2i_wq = (const float*)d_in[26];
  const float* q2i_wk = (const float*)d_in[27];
  const float* q2i_wv = (const float*)d_in[28];
  const float* q2i_wo = (const float*)d_in[29];
  const float* i2q_bo = (const float*)d_in[30];
  const float* q2i_bo = (const float*)d_in[31];
  const float* mlp_w  = (const float*)d_in[32];
  const float* mlp_b  = (const float*)d_in[33];
  const float* g_i2t  = (const float*)d_in[34];
  const float* g_t2i  = (const float*)d_in[35];

  float* out  = (float*)d_out;
  float* simP = out + (size_t)BB*NN*DD;
  float* simN = simP + (size_t)BB*NN;

  char* w8 = (char*)d_ws;
  size_t off = 0;
  auto take = [&](size_t bytes)->void*{
    void* p = (void*)(w8 + off);
    off += (bytes + 255) & ~(size_t)255;
    return p;
  };
  float* part   = (float*)take((size_t)BB*32*2*DD*4);
  float* pcnt   = (float*)take((size_t)BB*32*2*4);
  float* posq   = (float*)take((size_t)BB*2*DD*4);
  float* vvec   = (float*)take((size_t)BB*2*DD*4);
  float* cscal  = (float*)take((size_t)BB*2*4);
  int*   idxb   = (int*)take((size_t)BB*2*256*4);
  float* wb     = (float*)take((size_t)BB*2*256*4);
  float* node   = (float*)take((size_t)BB*384*DD*4);
  float* gA     = (float*)take((size_t)BB*384*DD*4);   // also t3
  float* gadjP  = (float*)take((size_t)BB*256*256*4);
  float* gadjN  = (float*)take((size_t)BB*128*128*4);
  float* query  = (float*)take((size_t)BB*384*DD*4);   // also t1 (t1 dead before query written)
  float* query2 = (float*)take((size_t)BB*384*DD*4);   // also t2
  unsigned short* xhatq  = (unsigned short*)take((size_t)BB*384*DD*2);
  unsigned short* qh     = (unsigned short*)take((size_t)BB*384*DD*2);
  unsigned short* attnZ  = (unsigned short*)take((size_t)BB*384*DD*2);
  unsigned short* xhatq2 = (unsigned short*)take((size_t)BB*384*DD*2);
  unsigned short* kv2    = (unsigned short*)take((size_t)BB*384*512*2);
  unsigned short* xhat   = (unsigned short*)take((size_t)BB*NN*DD*2);
  unsigned short* kvq    = (unsigned short*)take((size_t)BB*NN*768*2);
  float* featb2 = (float*)take((size_t)BB*NN*DD*4);
  float* Mpart  = (float*)take((size_t)BB*HH*8*384*4);
  float* Lpart  = (float*)take((size_t)BB*HH*8*384*4);
  unsigned short* wTq1  = (unsigned short*)take((size_t)65536*2);
  unsigned short* wTbig = (unsigned short*)take((size_t)3*65536*2);
  unsigned short* wTkv2 = (unsigned short*)take((size_t)2*65536*2);
  unsigned short* wTmlp = (unsigned short*)take((size_t)65536*2);
  unsigned short* wTo1  = (unsigned short*)take((size_t)65536*2);
  unsigned short* wTo2  = (unsigned short*)take((size_t)65536*2);
  float* biasQ1  = (float*)take(256*4);
  float* biasBig = (float*)take(768*4);
  float* biasKV2 = (float*)take(512*4);
  float* biasMlp = (float*)take(256*4);
  // overlays (disjoint lifetimes):
  float* t1 = query;            // dead before GCN writes query
  float* t2 = query2;           // dead before (c) writes query2
  float* t3 = gA;               // gA dead after gadj
  unsigned short* attn2 = xhat; // xhat dead after fused projection (b)
  unsigned short* xhat5 = kvq;  // kvq dead after q2i flash
  float* Opart = featb2;        // featb2 written only at (e), after combine

  const long sQ  = 384L*DD;
  const long sX  = (long)NN*DD;
  const float* NF = nullptr;

  // ---- weight folds (every call; cheap) ----
  FoldArgs fa;
  fa.W[0]=i2q_wq; fa.g[0]=ln1_g; fa.BT[0]=wTq1;
  fa.W[1]=i2q_wk; fa.g[1]=ln2_g; fa.BT[1]=wTbig;
  fa.W[2]=i2q_wv; fa.g[2]=ln2_g; fa.BT[2]=wTbig + 256*256;
  fa.W[3]=q2i_wq; fa.g[3]=ln3_g; fa.BT[3]=wTbig + 512*256;
  fa.W[4]=q2i_wk; fa.g[4]=ln4_g; fa.BT[4]=wTkv2;
  fa.W[5]=q2i_wv; fa.g[5]=ln4_g; fa.BT[5]=wTkv2 + 256*256;
  fa.W[6]=mlp_w;  fa.g[6]=ln5_g; fa.BT[6]=wTmlp;
  fa.W[7]=i2q_wo; fa.g[7]=nullptr; fa.BT[7]=wTo1;
  fa.W[8]=q2i_wo; fa.g[8]=nullptr; fa.BT[8]=wTo2;
  fold_w<<<dim3(16,9), 256, 0, stream>>>(fa);
  BiasArgs ba;
  ba.W[0]=i2q_wq; ba.b[0]=ln1_b; ba.addb[0]=nullptr; ba.out[0]=biasQ1;
  ba.W[1]=i2q_wk; ba.b[1]=ln2_b; ba.addb[1]=nullptr; ba.out[1]=biasBig;
  ba.W[2]=i2q_wv; ba.b[2]=ln2_b; ba.addb[2]=nullptr; ba.out[2]=biasBig+256;
  ba.W[3]=q2i_wq; ba.b[3]=ln3_b; ba.addb[3]=nullptr; ba.out[3]=biasBig+512;
  ba.W[4]=q2i_wk; ba.b[4]=ln4_b; ba.addb[4]=nullptr; ba.out[4]=biasKV2;
  ba.W[5]=q2i_wv; ba.b[5]=ln4_b; ba.addb[5]=nullptr; ba.out[5]=biasKV2+256;
  ba.W[6]=mlp_w;  ba.b[6]=ln5_b; ba.addb[6]=mlp_b;   ba.out[6]=biasMlp;
  fold_b<<<7, 256, 0, stream>>>(ba);

  // ---- stats / sims / topk / gather ----
  stats_part<<<dim3(32, BB), 256, 0, stream>>>(x, mask, part, pcnt);
  stats_final<<<BB, 256, 0, stream>>>(part, pcnt, posq);
  sim_vec<<<BB, 256, 0, stream>>>(sim_p_w, sim_p_b, sim_n_w, sim_n_b, posq, vvec, cscal);
  sim_kernel<<<dim3(NN/4, BB), 256, 0, stream>>>(x, vvec, cscal, simP, simN);
  topk_kernel<<<dim3(2, BB), 512, 0, stream>>>(simP, simN, idxb, wb);
  gather_nodes<<<dim3(KPP+KNN, BB), 256, 0, stream>>>(x, idxb, wb, node);

  // ---- GCN (pos/neg paired) ----
  GP z; z.M = 0; z.N = 0; z.K = 32; z.A=node; z.B=node; z.C=gA; z.sAb=0; z.sBb=0; z.sCb=0;
  z.lda=256; z.ldb=256; z.ldc=256; z.alpha=1.f; z.flags=0;
  // g1: gA = node @ adj_w   (stacked M=384)
  {
    GP p0 = { node, 384L*DD, 256, adj_w, 0, 256, gA, 384L*DD, 256, 384, 256, 256, 1.f, 0 };
    gemm_dual<<<dim3(4,6,BB), 256, 0, stream>>>(p0, z);
  }
  // gadj = softmax( gA @ node^T * scale )
  {
    GP p0 = { gA, 384L*DD, 256, node, 384L*DD, 256, gadjP, 65536L, 256, 256, 256, 256, 0.0625f, FLAG_TRANSB };
    GP p1 = { gA + 256L*DD, 384L*DD, 256, node + 256L*DD, 384L*DD, 256, gadjN, 16384L, 128, 128, 128, 256, 0.0625f, FLAG_TRANSB };
    gemm_dual<<<dim3(4,4,2*BB), 256, 0, stream>>>(p0, p1);
  }
  softmax_dual<<<768, 256, 0, stream>>>(gadjP, 256, 256, 65536L, BB*256,
                                        gadjN, 128, 128, 16384L, BB*128);
  // t1 = node @ w1
  {
    GP p0 = { node, 384L*DD, 256, gnn_p_w1, 0, 256, t1, 384L*DD, 256, 256, 256, 256, 1.f, 0 };
    GP p1 = { node + 256L*DD, 384L*DD, 256, gnn_n_w1, 0, 256, t1 + 256L*DD, 384L*DD, 256, 128, 256, 256, 1.f, 0 };
    gemm_dual<<<dim3(4,4,2*BB), 256, 0, stream>>>(p0, p1);
  }
  // t2 = relu(adj @ t1)
  {
    GP p0 = { gadjP, 65536L, 256, t1, 384L*DD, 256, t2, 384L*DD, 256, 256, 256, 256, 1.f, FLAG_RELU };
    GP p1 = { gadjN, 16384L, 128, t1 + 256L*DD, 384L*DD, 256, t2 + 256L*DD, 384L*DD, 256, 128, 256, 128, 1.f, FLAG_RELU };
    gemm_dual<<<dim3(4,4,2*BB), 256, 0, stream>>>(p0, p1);
  }
  // t3 = t2 @ w2
  {
    GP p0 = { t2, 384L*DD, 256, gnn_p_w2, 0, 256, t3, 384L*DD, 256, 256, 256, 256, 1.f, 0 };
    GP p1 = { t2 + 256L*DD, 384L*DD, 256, gnn_n_w2, 0, 256, t3 + 256L*DD, 384L*DD, 256, 128, 256, 256, 1.f, 0 };
    gemm_dual<<<dim3(4,4,2*BB), 256, 0, stream>>>(p0, p1);
  }
  // query = adj @ t3
  {
    GP p0 = { gadjP, 65536L, 256, t3, 384L*DD, 256, query, 384L*DD, 256, 256, 256, 256, 1.f, 0 };
    GP p1 = { gadjN, 16384L, 128, t3 + 256L*DD, 384L*DD, 256, query + 256L*DD, 384L*DD, 256, 128, 256, 128, 1.f, 0 };
    gemm_dual<<<dim3(4,4,2*BB), 256, 0, stream>>>(p0, p1);
  }
  add_posemb<<<dim3(384, BB), 256, 0, stream>>>(query, idxb, pos_emb);

  // ---- LN cores ----
  rownorm_kernel<<<BB*NN/4, 256, 0, stream>>>(x, xhat, BB*NN);
  rownorm_kernel<<<BB*384/4, 256, 0, stream>>>(query, xhatq, BB*384);

  // (a) qh = xhatq @ wq' + b'
  gemm128<unsigned short,false,false><<<dim3(2,3,BB),256,0,stream>>>(
      xhatq, sQ, wTq1, qh, sQ, 256, NF, 0, biasQ1, NF);
  // (b) [kh|vh|qh2] = xhat @ [wk'|wv'|wq2'] + b'
  gemm128<unsigned short,false,false><<<dim3(6,32,BB),256,0,stream>>>(
      xhat, sX, wTbig, kvq, (long)NN*768, 768, NF, 0, biasBig, NF);
  // i2q flash (K-split 8) + combine
  flash_kernel<<<dim3(6*8, HH, BB), 256, 0, stream>>>(
      qh, sQ, 256, kvq, kvq + 256, (long)NN*768, 768,
      attnZ, sQ, Opart, Mpart, Lpart, 384, NN, 8, 0.125f);
  flash_combine<<<BB*HH*384/4, 256, 0, stream>>>(Opart, Mpart, Lpart, attnZ, sQ, 384, 8);
  // (c) query2 = query + g_i2t .* (attnZ @ wo + bo)
  gemm128<float,true,true><<<dim3(2,3,BB),256,0,stream>>>(
      attnZ, sQ, wTo1, query2, sQ, 256, query, sQ, i2q_bo, g_i2t);

  // ---- q2i ----
  rownorm_kernel<<<BB*384/4, 256, 0, stream>>>(query2, xhatq2, BB*384);
  // (d) [k2|v2] = xhatq2 @ [wk2'|wv2'] + b'
  gemm128<unsigned short,false,false><<<dim3(4,3,BB),256,0,stream>>>(
      xhatq2, sQ, wTkv2, kv2, 384L*512, 512, NF, 0, biasKV2, NF);
  flash_kernel<<<dim3(NN/64, HH, BB), 256, 0, stream>>>(
      kvq + 512, (long)NN*768, 768, kv2, kv2 + 256, 384L*512, 512,
      attn2, sX, NF ? nullptr : nullptr, nullptr, nullptr, NN, 384, 1, 0.125f);
  // (e) featb2 = x + g_t2i .* (attn2 @ wo + bo)
  gemm128<float,true,true><<<dim3(2,32,BB),256,0,stream>>>(
      attn2, sX, wTo2, featb2, sX, 256, x, sX, q2i_bo, g_t2i);

  // ---- final MLP ----
  rownorm_kernel<<<BB*NN/4, 256, 0, stream>>>(featb2, xhat5, BB*NN);
  // (f) out = featb2 + xhat5 @ mlp' + b'
  gemm128<float,true,false><<<dim3(2,32,BB),256,0,stream>>>(
      xhat5, sX, wTmlp, out, sX, 256, featb2, sX, biasMlp, NF);
}